// Round 1
// baseline (2666.888 us; speedup 1.0000x reference)
//
#include <hip/hip_runtime.h>
#include <hip/hip_bf16.h>
#include <hip/hip_cooperative_groups.h>

namespace cg = cooperative_groups;

typedef __attribute__((ext_vector_type(8))) short short8;
typedef __attribute__((ext_vector_type(4))) float f32x4;

#define Hh   512
#define Bb   64
#define Tt   64
#define Vv   10000
#define VPAD 10112

__device__ __forceinline__ unsigned short f2bf(float f){
  union { float f; unsigned u; } v; v.f = f;
  unsigned r = (v.u + 0x7FFFu + ((v.u >> 16) & 1u)) >> 16;
  return (unsigned short)r;
}

// A_pre[m=(t*64+b)][k] bf16 : k<256 -> emb[tok[b,t]][k], else img[b][k-256]
__global__ void build_Apre(const int* __restrict__ tok, const float* __restrict__ emb,
                           const float* __restrict__ img, unsigned short* __restrict__ A){
  int idx = blockIdx.x*256 + threadIdx.x;      // 4096*512 = 2,097,152
  int m = idx >> 9, k = idx & 511;
  int b = m & 63, t = m >> 6;
  float v;
  if (k < 256) v = emb[(size_t)tok[b*64 + t]*256 + k];
  else         v = img[b*256 + (k-256)];
  A[idx] = f2bf(v);
}

// WxT[i=(g*512+h)][k] = W_g[(512+k)*512 + h]  (bf16), via LDS transpose
__global__ void build_WxT(const float* __restrict__ Wu, const float* __restrict__ Wr,
                          const float* __restrict__ Wc, unsigned short* __restrict__ WxT){
  __shared__ float tile[64][65];
  int kb = blockIdx.x, hb = blockIdx.y, g = blockIdx.z;
  const float* Wg = g==0 ? Wu : (g==1 ? Wr : Wc);
  int tid = threadIdx.x, c = tid & 63, r4 = tid >> 6;
  #pragma unroll
  for (int i=0;i<16;i++){
    int kr = r4 + i*4;
    tile[kr][c] = Wg[(size_t)(512 + kb*64 + kr)*512 + hb*64 + c];
  }
  __syncthreads();
  #pragma unroll
  for (int i=0;i<16;i++){
    int hr = r4 + i*4;
    WxT[(size_t)(g*512 + hb*64 + hr)*512 + kb*64 + c] = f2bf(tile[c][hr]);
  }
}

// WoutT[v][h] bf16 (v padded to 10112, pad rows zero)
__global__ void build_WoutT(const float* __restrict__ Wo, unsigned short* __restrict__ WT){
  __shared__ float tile[64][65];
  int vb = blockIdx.x, hb = blockIdx.y;
  int tid = threadIdx.x, c = tid & 63, r4 = tid >> 6;
  #pragma unroll
  for (int i=0;i<16;i++){
    int hr = r4 + i*4;
    int v = vb*64 + c;
    tile[hr][c] = (v < Vv) ? Wo[(size_t)(hb*64 + hr)*Vv + v] : 0.f;
  }
  __syncthreads();
  #pragma unroll
  for (int i=0;i<16;i++){
    int vr = r4 + i*4;
    WT[(size_t)(vb*64 + vr)*512 + hb*64 + c] = f2bf(tile[c][vr]);
  }
}

// statesT[0][h][b] = initial[0][b][h]
__global__ void build_s0(const float* __restrict__ init, float* __restrict__ statesT){
  int idx = blockIdx.x*256 + threadIdx.x;  // 32768
  int hh = idx >> 6, b = idx & 63;
  statesT[idx] = init[b*512 + hh];
}

// C = P @ Q^T with P[Mdim][512], Q[Ndim][512] bf16 row-major.
// MODE 0: pre-GEMM  P=WxT(1536), Q=Apre(4096); C -> preT[t][g][h][b], +b_u/+b_r by g
// MODE 1: logits    P=Alog(4096), Q=WoutT(10112); C -> out[b][t][v], +b_out, guard v<10000
template<int MODE>
__global__ __launch_bounds__(256) void gemm_bf16(
    const unsigned short* __restrict__ P, const unsigned short* __restrict__ Q,
    float* __restrict__ C, const float* __restrict__ bias0, const float* __restrict__ bias1)
{
  __shared__ __align__(16) unsigned short As[128*72];
  __shared__ __align__(16) unsigned short Bs[128*72];
  int tid = threadIdx.x;
  int lane = tid & 63, wave = tid >> 6;
  int wm = wave >> 1, wn = wave & 1;
  int m0 = blockIdx.y * 128, n0 = blockIdx.x * 128;
  f32x4 acc[4][4] = {};
  int r = tid >> 1, seg = tid & 1;
  const uint4* gp = (const uint4*)(P + (size_t)(m0 + r)*512 + seg*32);
  const uint4* gq = (const uint4*)(Q + (size_t)(n0 + r)*512 + seg*32);
  uint4* lp = (uint4*)(As + r*72 + seg*32);
  uint4* lq = (uint4*)(Bs + r*72 + seg*32);
  for (int kt = 0; kt < 8; ++kt) {
    uint4 a0 = gp[kt*8+0], a1 = gp[kt*8+1], a2 = gp[kt*8+2], a3 = gp[kt*8+3];
    uint4 b0 = gq[kt*8+0], b1 = gq[kt*8+1], b2 = gq[kt*8+2], b3 = gq[kt*8+3];
    if (kt) __syncthreads();
    lp[0]=a0; lp[1]=a1; lp[2]=a2; lp[3]=a3;
    lq[0]=b0; lq[1]=b1; lq[2]=b2; lq[3]=b3;
    __syncthreads();
    #pragma unroll
    for (int ks = 0; ks < 2; ++ks) {
      short8 a[4], b[4];
      int ko = ks*32 + (lane>>4)*8;
      #pragma unroll
      for (int f=0; f<4; ++f){
        a[f] = *(const short8*)(As + (wm*64 + f*16 + (lane&15))*72 + ko);
        b[f] = *(const short8*)(Bs + (wn*64 + f*16 + (lane&15))*72 + ko);
      }
      #pragma unroll
      for (int i=0;i<4;++i)
        #pragma unroll
        for (int j=0;j<4;++j)
          acc[i][j] = __builtin_amdgcn_mfma_f32_16x16x32_bf16(a[i], b[j], acc[i][j], 0,0,0);
    }
  }
  int rowbase = (lane>>4)*4;
  int col = lane & 15;
  #pragma unroll
  for (int i=0;i<4;++i){
    #pragma unroll
    for (int j=0;j<4;++j){
      int nJ = n0 + wn*64 + j*16 + col;
      #pragma unroll
      for (int rr=0; rr<4; ++rr){
        int mI = m0 + wm*64 + i*16 + rowbase + rr;
        float v = acc[i][j][rr];
        if (MODE == 0) {
          int g = mI >> 9, hh = mI & 511;
          if (g == 0) v += bias0[hh];
          else if (g == 1) v += bias1[hh];
          C[(size_t)(nJ>>6)*98304 + (size_t)mI*64 + (nJ&63)] = v;
        } else {
          if (nJ < Vv) {
            v += bias0[nJ];
            int t = mI >> 6, b = mI & 63;
            C[(size_t)b*640000 + (size_t)t*Vv + nJ] = v;
          }
        }
      }
    }
  }
}

// Cooperative recurrence, f32. 256 blocks x 512 thr. Block owns h = blk*2 .. +1.
// wave = (c, kq): c = wave>>2 (col), kq = wave&3 (k-quarter of 128).
__global__ __launch_bounds__(512) void recur_kernel(
    const float* __restrict__ preT, const float* __restrict__ Wu,
    const float* __restrict__ Wr, const float* __restrict__ Wc,
    const float* __restrict__ bc, float* __restrict__ statesT)
{
  __shared__ float wL[3*2*512];
  __shared__ float red[2][4][3][64];
  int tid = threadIdx.x;
  int lane = tid & 63, wave = tid >> 6;
  int c = wave >> 2, kq = wave & 3;
  int blk = blockIdx.x;
  for (int idx = tid; idx < 3072; idx += 512){
    int g = idx >> 10, rem = idx & 1023, cc = rem >> 9, k = rem & 511;
    const float* Wg = g==0 ? Wu : (g==1 ? Wr : Wc);
    wL[idx] = Wg[(size_t)k*512 + blk*2 + cc];
  }
  __syncthreads();
  int h = blk*2 + c;
  const float* w0 = &wL[0*1024 + c*512];
  const float* w1 = &wL[1*1024 + c*512];
  const float* w2 = &wL[2*1024 + c*512];
  float bch = bc[h];
  cg::grid_group grid = cg::this_grid();
  for (int t = 0; t < 64; ++t) {
    const float* sT = statesT + (size_t)t*32768;
    float aU=0.f, aR=0.f, aC=0.f;
    int k0 = kq*128;
    #pragma unroll 4
    for (int k = 0; k < 128; ++k){
      float s = sT[(k0+k)*64 + lane];
      aU += s * w0[k0+k];
      aR += s * w1[k0+k];
      aC += s * w2[k0+k];
    }
    red[c][kq][0][lane]=aU; red[c][kq][1][lane]=aR; red[c][kq][2][lane]=aC;
    __syncthreads();
    if (kq == 0){
      float U = red[c][0][0][lane]+red[c][1][0][lane]+red[c][2][0][lane]+red[c][3][0][lane];
      float R = red[c][0][1][lane]+red[c][1][1][lane]+red[c][2][1][lane]+red[c][3][1][lane];
      float Cv= red[c][0][2][lane]+red[c][1][2][lane]+red[c][2][2][lane]+red[c][3][2][lane];
      const float* pt = preT + (size_t)t*98304;
      float u  = 1.f/(1.f + __expf(-(U + pt[0*32768 + h*64 + lane])));
      float gr = 1.f/(1.f + __expf(-(R + pt[1*32768 + h*64 + lane])));
      float rv = tanhf(gr * (Cv + pt[2*32768 + h*64 + lane]) + bch);
      float sold = sT[h*64 + lane];
      statesT[(size_t)(t+1)*32768 + h*64 + lane] = rv*(1.f-u) + u*sold;
    }
    grid.sync();
  }
}

// A_logits[m=(t*64+b)][h] bf16 from statesT[t+1][h][b]
__global__ void states_to_A(const float* __restrict__ statesT, unsigned short* __restrict__ A){
  __shared__ float tile[64][65];
  int hb = blockIdx.x, t = blockIdx.y;
  int tid = threadIdx.x, c = tid & 63, r4 = tid >> 6;
  const float* s = statesT + (size_t)(t+1)*32768 + hb*64*64;
  #pragma unroll
  for (int i=0;i<16;i++){
    int hr = r4 + i*4;
    tile[hr][c] = s[hr*64 + c];
  }
  __syncthreads();
  #pragma unroll
  for (int i=0;i<16;i++){
    int br = r4 + i*4;
    A[(size_t)(t*64 + br)*512 + hb*64 + c] = f2bf(tile[c][br]);
  }
}

// out_final[b*512+h] = statesT[64][h][b]
__global__ void final_state(const float* __restrict__ statesT, float* __restrict__ out){
  int idx = blockIdx.x*256 + threadIdx.x;  // 32768
  int b = idx >> 9, hh = idx & 511;
  out[idx] = statesT[(size_t)64*32768 + hh*64 + b];
}

extern "C" void kernel_launch(void* const* d_in, const int* in_sizes, int n_in,
                              void* d_out, int out_size, void* d_ws, size_t ws_size,
                              hipStream_t stream){
  const int*   tok  = (const int*)  d_in[0];
  const float* img  = (const float*)d_in[1];
  const float* init = (const float*)d_in[2];
  const float* emb  = (const float*)d_in[3];
  const float* Wu   = (const float*)d_in[4];
  const float* bu   = (const float*)d_in[5];
  const float* Wr   = (const float*)d_in[6];
  const float* br   = (const float*)d_in[7];
  const float* Wc   = (const float*)d_in[8];
  const float* bcp  = (const float*)d_in[9];
  const float* Wo   = (const float*)d_in[10];
  const float* bo   = (const float*)d_in[11];
  float* out = (float*)d_out;

  char* ws = (char*)d_ws;
  size_t off = 0;
  unsigned short* Apre = (unsigned short*)(ws + off); off += (size_t)4096*512*2;      // 4 MB
  unsigned short* WxT  = (unsigned short*)(ws + off); off += (size_t)1536*512*2;      // 1.5 MB
  float* preT          = (float*)(ws + off);          off += (size_t)64*3*512*64*4;   // 25.2 MB
  float* statesT       = (float*)(ws + off);          off += (size_t)65*512*64*4;     // 8.5 MB
  unsigned short* Alog = (unsigned short*)(ws + off); off += (size_t)4096*512*2;      // 4 MB
  unsigned short* WoT  = (unsigned short*)(ws + off); off += (size_t)VPAD*512*2;      // 10.4 MB

  build_Apre <<<8192, 256, 0, stream>>>(tok, emb, img, Apre);
  build_WxT  <<<dim3(8,8,3), 256, 0, stream>>>(Wu, Wr, Wc, WxT);
  build_WoutT<<<dim3(158,8), 256, 0, stream>>>(Wo, WoT);
  build_s0   <<<128, 256, 0, stream>>>(init, statesT);

  gemm_bf16<0><<<dim3(32,12), 256, 0, stream>>>(WxT, Apre, preT, bu, br);

  void* args[6] = { (void*)&preT, (void*)&Wu, (void*)&Wr, (void*)&Wc, (void*)&bcp, (void*)&statesT };
  hipLaunchCooperativeKernel((void*)recur_kernel, dim3(256), dim3(512), args, 0, stream);

  states_to_A<<<dim3(8,64), 256, 0, stream>>>(statesT, Alog);
  final_state<<<128, 256, 0, stream>>>(statesT, out + (size_t)40960000);

  gemm_bf16<1><<<dim3(79,32), 256, 0, stream>>>(Alog, WoT, out, bo, nullptr);
}

// Round 2
// 1076.063 us; speedup vs baseline: 2.4784x; 2.4784x over previous
//
#include <hip/hip_runtime.h>
#include <hip/hip_bf16.h>

typedef __attribute__((ext_vector_type(8))) short short8;
typedef __attribute__((ext_vector_type(4))) float f32x4;

#define Vv   10000
#define VPAD 10112

__device__ __forceinline__ unsigned short f2bf(float f){
  union { float f; unsigned u; } v; v.f = f;
  unsigned r = (v.u + 0x7FFFu + ((v.u >> 16) & 1u)) >> 16;
  return (unsigned short)r;
}

// A_pre[m=(t*64+b)][k] bf16 : k<256 -> emb[tok[b,t]][k], else img[b][k-256]
__global__ void build_Apre(const int* __restrict__ tok, const float* __restrict__ emb,
                           const float* __restrict__ img, unsigned short* __restrict__ A){
  int idx = blockIdx.x*256 + threadIdx.x;      // 4096*512
  int m = idx >> 9, k = idx & 511;
  int b = m & 63, t = m >> 6;
  float v;
  if (k < 256) v = emb[(size_t)tok[b*64 + t]*256 + k];
  else         v = img[b*256 + (k-256)];
  A[idx] = f2bf(v);
}

// WxT[i=(g*512+h)][k] = W_g[(512+k)*512 + h]  (bf16) -- x-part rows
__global__ void build_WxT(const float* __restrict__ Wu, const float* __restrict__ Wr,
                          const float* __restrict__ Wc, unsigned short* __restrict__ WxT){
  __shared__ float tile[64][65];
  int kb = blockIdx.x, hb = blockIdx.y, g = blockIdx.z;
  const float* Wg = g==0 ? Wu : (g==1 ? Wr : Wc);
  int tid = threadIdx.x, c = tid & 63, r4 = tid >> 6;
  #pragma unroll
  for (int i=0;i<16;i++){
    int kr = r4 + i*4;
    tile[kr][c] = Wg[(size_t)(512 + kb*64 + kr)*512 + hb*64 + c];
  }
  __syncthreads();
  #pragma unroll
  for (int i=0;i<16;i++){
    int hr = r4 + i*4;
    WxT[(size_t)(g*512 + hb*64 + hr)*512 + kb*64 + c] = f2bf(tile[c][hr]);
  }
}

// WrT[g][h][k] = W_g[k*512 + h] f32 -- state-part rows (k<512), transposed
__global__ void build_WrT(const float* __restrict__ Wu, const float* __restrict__ Wr,
                          const float* __restrict__ Wc, float* __restrict__ WrT){
  __shared__ float tile[64][65];
  int kb = blockIdx.x, hb = blockIdx.y, g = blockIdx.z;
  const float* Wg = g==0 ? Wu : (g==1 ? Wr : Wc);
  int tid = threadIdx.x, c = tid & 63, r4 = tid >> 6;
  #pragma unroll
  for (int i=0;i<16;i++){
    int kr = r4 + i*4;
    tile[kr][c] = Wg[(size_t)(kb*64 + kr)*512 + hb*64 + c];
  }
  __syncthreads();
  #pragma unroll
  for (int i=0;i<16;i++){
    int hr = r4 + i*4;
    WrT[((size_t)g*512 + hb*64 + hr)*512 + kb*64 + c] = tile[c][hr];
  }
}

// WoutT[v][h] bf16 (v padded to 10112, pad rows zero)
__global__ void build_WoutT(const float* __restrict__ Wo, unsigned short* __restrict__ WT){
  __shared__ float tile[64][65];
  int vb = blockIdx.x, hb = blockIdx.y;
  int tid = threadIdx.x, c = tid & 63, r4 = tid >> 6;
  #pragma unroll
  for (int i=0;i<16;i++){
    int hr = r4 + i*4;
    int v = vb*64 + c;
    tile[hr][c] = (v < Vv) ? Wo[(size_t)(hb*64 + hr)*Vv + v] : 0.f;
  }
  __syncthreads();
  #pragma unroll
  for (int i=0;i<16;i++){
    int vr = r4 + i*4;
    WT[(size_t)(vb*64 + vr)*512 + hb*64 + c] = f2bf(tile[c][vr]);
  }
}

// sb[0][g][h][b] = init[(g*8+b)*512 + h]
__global__ void build_s0T(const float* __restrict__ init, float* __restrict__ sb){
  int idx = blockIdx.x*256 + threadIdx.x;  // 32768
  int bg = idx >> 9, h = idx & 511;
  int g = bg >> 3, b = bg & 7;
  sb[g*4096 + h*8 + b] = init[idx];
}

// C = P @ Q^T, P[M][512], Q[N][512] bf16 row-major.
// MODE 0: pre-GEMM  P=WxT(1536), Q=Apre(4096); C -> preT[t][g][h][b], +b_u/+b_r by g
// MODE 1: logits    P=Alog(4096), Q=WoutT(10112); C -> out[b][t][v], +b_out, v<10000
template<int MODE>
__global__ __launch_bounds__(256) void gemm_bf16(
    const unsigned short* __restrict__ P, const unsigned short* __restrict__ Q,
    float* __restrict__ C, const float* __restrict__ bias0, const float* __restrict__ bias1)
{
  __shared__ __align__(16) unsigned short As[128*72];
  __shared__ __align__(16) unsigned short Bs[128*72];
  int tid = threadIdx.x;
  int lane = tid & 63, wave = tid >> 6;
  int wm = wave >> 1, wn = wave & 1;
  int m0 = blockIdx.y * 128, n0 = blockIdx.x * 128;
  f32x4 acc[4][4] = {};
  int r = tid >> 1, seg = tid & 1;
  const uint4* gp = (const uint4*)(P + (size_t)(m0 + r)*512 + seg*32);
  const uint4* gq = (const uint4*)(Q + (size_t)(n0 + r)*512 + seg*32);
  uint4* lp = (uint4*)(As + r*72 + seg*32);
  uint4* lq = (uint4*)(Bs + r*72 + seg*32);
  for (int kt = 0; kt < 8; ++kt) {
    uint4 a0 = gp[kt*8+0], a1 = gp[kt*8+1], a2 = gp[kt*8+2], a3 = gp[kt*8+3];
    uint4 b0 = gq[kt*8+0], b1 = gq[kt*8+1], b2 = gq[kt*8+2], b3 = gq[kt*8+3];
    if (kt) __syncthreads();
    lp[0]=a0; lp[1]=a1; lp[2]=a2; lp[3]=a3;
    lq[0]=b0; lq[1]=b1; lq[2]=b2; lq[3]=b3;
    __syncthreads();
    #pragma unroll
    for (int ks = 0; ks < 2; ++ks) {
      short8 a[4], b[4];
      int ko = ks*32 + (lane>>4)*8;
      #pragma unroll
      for (int f=0; f<4; ++f){
        a[f] = *(const short8*)(As + (wm*64 + f*16 + (lane&15))*72 + ko);
        b[f] = *(const short8*)(Bs + (wn*64 + f*16 + (lane&15))*72 + ko);
      }
      #pragma unroll
      for (int i=0;i<4;++i)
        #pragma unroll
        for (int j=0;j<4;++j)
          acc[i][j] = __builtin_amdgcn_mfma_f32_16x16x32_bf16(a[i], b[j], acc[i][j], 0,0,0);
    }
  }
  int rowbase = (lane>>4)*4;
  int col = lane & 15;
  #pragma unroll
  for (int i=0;i<4;++i){
    #pragma unroll
    for (int j=0;j<4;++j){
      int nJ = n0 + wn*64 + j*16 + col;
      #pragma unroll
      for (int rr=0; rr<4; ++rr){
        int mI = m0 + wm*64 + i*16 + rowbase + rr;
        float v = acc[i][j][rr];
        if (MODE == 0) {
          int g = mI >> 9, hh = mI & 511;
          if (g == 0) v += bias0[hh];
          else if (g == 1) v += bias1[hh];
          C[(size_t)(nJ>>6)*98304 + (size_t)mI*64 + (nJ&63)] = v;
        } else {
          if (nJ < Vv) {
            v += bias0[nJ];
            int t = mI >> 6, b = mI & 63;
            C[(size_t)b*640000 + (size_t)t*Vv + nJ] = v;
          }
        }
      }
    }
  }
}

// Recurrence: 256 wgs x 512 thr, cooperative. Group = blockIdx&7 (XCD-pinned),
// 32 wgs/group handle 8 batches; wg owns 16 h-cols. Weights in 96 VGPRs f32.
// Sync: monotonic release/acquire counter per group (no grid.sync).
__global__ __launch_bounds__(512, 2) void recur2(
    const float* __restrict__ WrT, const float* __restrict__ preT,
    const float* __restrict__ bc, float* __restrict__ sb,
    unsigned short* __restrict__ Alog, float* __restrict__ fstate,
    unsigned int* __restrict__ ctr)
{
  __shared__ __align__(16) float sL[4096];       // state [k=512][b=8]
  __shared__ __align__(16) float red[24*512];    // [slot][tid]
  int tid = threadIdx.x;
  int lane = tid & 63;
  int wv = tid >> 6;          // h'' 0..7 (wave id)
  int bs = lane >> 5;         // 0..1
  int ks = lane & 31;         // k-split lane
  int wg = blockIdx.x;
  int g = wg & 7;             // group (XCD heuristic only; correctness from fences)
  int wgi = wg >> 3;          // 0..31
  int h0 = wgi * 16;

  // weights: w[hh][g3][i] = W_g3[k=i*32+ks][h0+wv*2+hh], loaded once
  float w[2][3][16];
  #pragma unroll
  for (int hh=0; hh<2; ++hh)
    #pragma unroll
    for (int g3=0; g3<3; ++g3) {
      const float* wp = WrT + ((size_t)g3*512 + h0 + wv*2 + hh)*512 + ks;
      #pragma unroll
      for (int i=0; i<16; ++i) w[hh][g3][i] = wp[i*32];
    }

  // reader-role constants (threads 0..127): tid = hl*8 + b  (b fastest)
  int rb  = tid & 7;
  int rhl = tid >> 3;
  int rh  = h0 + rhl;
  int rbg = g*8 + rb;
  float bch = (tid < 128) ? bc[rh] : 0.f;

  unsigned int tgt = 32;
  for (int t = 0; t < 64; ++t) {
    // early loads: pre-activations for this step (state-independent)
    float ptU=0.f, ptR=0.f, ptC=0.f;
    if (tid < 128) {
      const float* pt = preT + (size_t)t*98304;
      ptU = pt[0*32768 + rh*64 + rbg];
      ptR = pt[1*32768 + rh*64 + rbg];
      ptC = pt[2*32768 + rh*64 + rbg];
    }
    // stage state -> LDS (16 KB, coalesced)
    const float* src = sb + (size_t)(t&1)*32768 + g*4096;
    f32x4 v0 = ((const f32x4*)src)[tid];
    f32x4 v1 = ((const f32x4*)src)[tid + 512];
    ((f32x4*)sL)[tid] = v0;
    ((f32x4*)sL)[tid + 512] = v1;
    __syncthreads();

    // partial dots: thread covers h'={wv*2,+1}, b={bs*4..+3}, k={i*32+ks}
    float acc[2][3][4];
    #pragma unroll
    for (int hh=0; hh<2; ++hh)
      #pragma unroll
      for (int g3=0; g3<3; ++g3)
        #pragma unroll
        for (int bb=0; bb<4; ++bb) acc[hh][g3][bb] = 0.f;
    #pragma unroll
    for (int i=0; i<16; ++i){
      f32x4 s4 = *(const f32x4*)&sL[(i*32+ks)*8 + bs*4];
      #pragma unroll
      for (int hh=0; hh<2; ++hh)
        #pragma unroll
        for (int g3=0; g3<3; ++g3)
          #pragma unroll
          for (int bb=0; bb<4; ++bb)
            acc[hh][g3][bb] += s4[bb] * w[hh][g3][i];
    }
    // slot-major reduction buffer: conflict-free writes, vector reads
    #pragma unroll
    for (int hh=0; hh<2; ++hh)
      #pragma unroll
      for (int g3=0; g3<3; ++g3)
        #pragma unroll
        for (int bb=0; bb<4; ++bb)
          red[(((hh*3)+g3)*4 + bb)*512 + tid] = acc[hh][g3][bb];
    __syncthreads();

    if (tid < 128) {
      int h2 = rhl >> 1, hh = rhl & 1, bs2 = rb >> 2, bb = rb & 3;
      int base = h2*64 + bs2*32;
      float U=0.f, R=0.f, Cv=0.f;
      #pragma unroll
      for (int j=0; j<8; ++j){
        f32x4 a = *(const f32x4*)&red[((hh*3+0)*4+bb)*512 + base + j*4];
        U += (a[0]+a[1]) + (a[2]+a[3]);
      }
      #pragma unroll
      for (int j=0; j<8; ++j){
        f32x4 a = *(const f32x4*)&red[((hh*3+1)*4+bb)*512 + base + j*4];
        R += (a[0]+a[1]) + (a[2]+a[3]);
      }
      #pragma unroll
      for (int j=0; j<8; ++j){
        f32x4 a = *(const f32x4*)&red[((hh*3+2)*4+bb)*512 + base + j*4];
        Cv += (a[0]+a[1]) + (a[2]+a[3]);
      }
      float gu = 1.f/(1.f + __expf(-(U + ptU)));
      float gr = 1.f/(1.f + __expf(-(R + ptR)));
      float rv = tanhf(gr * (Cv + ptC) + bch);
      float sold = sL[rh*8 + rb];
      float ns = rv*(1.f - gu) + gu*sold;
      sb[(size_t)((t+1)&1)*32768 + g*4096 + rh*8 + rb] = ns;   // contiguous per wg
      Alog[((size_t)(t*64) + rbg)*512 + rh] = f2bf(ns);
      if (t == 63) fstate[(size_t)rbg*512 + rh] = ns;
    }
    if (t < 63) {
      __syncthreads();   // all slice writes issued (vmcnt drained) before release
      if (tid == 0) {
        __hip_atomic_fetch_add(&ctr[g], 1u, __ATOMIC_RELEASE, __HIP_MEMORY_SCOPE_AGENT);
        while (__hip_atomic_load(&ctr[g], __ATOMIC_ACQUIRE, __HIP_MEMORY_SCOPE_AGENT) < tgt)
          __builtin_amdgcn_s_sleep(2);
      }
      tgt += 32;
      __syncthreads();
    }
  }
}

extern "C" void kernel_launch(void* const* d_in, const int* in_sizes, int n_in,
                              void* d_out, int out_size, void* d_ws, size_t ws_size,
                              hipStream_t stream){
  const int*   tok  = (const int*)  d_in[0];
  const float* img  = (const float*)d_in[1];
  const float* init = (const float*)d_in[2];
  const float* emb  = (const float*)d_in[3];
  const float* Wu   = (const float*)d_in[4];
  const float* bu   = (const float*)d_in[5];
  const float* Wr   = (const float*)d_in[6];
  const float* br   = (const float*)d_in[7];
  const float* Wc   = (const float*)d_in[8];
  const float* bcp  = (const float*)d_in[9];
  const float* Wo   = (const float*)d_in[10];
  const float* bo   = (const float*)d_in[11];
  float* out = (float*)d_out;

  char* ws = (char*)d_ws;
  size_t off = 0;
  unsigned short* Apre = (unsigned short*)(ws + off); off += (size_t)4096*512*2;      // 4 MB
  unsigned short* WxT  = (unsigned short*)(ws + off); off += (size_t)1536*512*2;      // 1.5 MB
  float* preT          = (float*)(ws + off);          off += (size_t)64*3*512*64*4;   // 25.2 MB
  unsigned short* Alog = (unsigned short*)(ws + off); off += (size_t)4096*512*2;      // 4 MB
  unsigned short* WoT  = (unsigned short*)(ws + off); off += (size_t)VPAD*512*2;      // 10.4 MB
  float* WrTbuf        = (float*)(ws + off);          off += (size_t)3*512*512*4;     // 3 MB
  float* sb            = (float*)(ws + off);          off += (size_t)2*8*4096*4;      // 256 KB
  unsigned int* ctr    = (unsigned int*)(ws + off);   off += 256;

  build_Apre <<<8192, 256, 0, stream>>>(tok, emb, img, Apre);
  build_WxT  <<<dim3(8,8,3), 256, 0, stream>>>(Wu, Wr, Wc, WxT);
  build_WrT  <<<dim3(8,8,3), 256, 0, stream>>>(Wu, Wr, Wc, WrTbuf);
  build_WoutT<<<dim3(158,8), 256, 0, stream>>>(Wo, WoT);
  build_s0T  <<<128, 256, 0, stream>>>(init, sb);

  gemm_bf16<0><<<dim3(32,12), 256, 0, stream>>>(WxT, Apre, preT, bu, br);

  hipMemsetAsync(ctr, 0, 256, stream);
  float* fstate = out + (size_t)40960000;
  void* args[7] = { (void*)&WrTbuf, (void*)&preT, (void*)&bcp, (void*)&sb,
                    (void*)&Alog, (void*)&fstate, (void*)&ctr };
  hipLaunchCooperativeKernel((void*)recur2, dim3(256), dim3(512), args, 0, stream);

  gemm_bf16<1><<<dim3(79,32), 256, 0, stream>>>(Alog, WoT, out, bo, nullptr);
}

// Round 3
// 656.319 us; speedup vs baseline: 4.0634x; 1.6395x over previous
//
#include <hip/hip_runtime.h>
#include <hip/hip_bf16.h>

typedef __attribute__((ext_vector_type(8))) short short8;
typedef __attribute__((ext_vector_type(4))) float f32x4;

#define Vv   10000
#define VPAD 10112

__device__ __forceinline__ unsigned short f2bf(float f){
  union { float f; unsigned u; } v; v.f = f;
  unsigned r = (v.u + 0x7FFFu + ((v.u >> 16) & 1u)) >> 16;
  return (unsigned short)r;
}

// A_pre[m=(t*64+b)][k] bf16 : k<256 -> emb[tok[b,t]][k], else img[b][k-256]
__global__ void build_Apre(const int* __restrict__ tok, const float* __restrict__ emb,
                           const float* __restrict__ img, unsigned short* __restrict__ A){
  int idx = blockIdx.x*256 + threadIdx.x;      // 4096*512
  int m = idx >> 9, k = idx & 511;
  int b = m & 63, t = m >> 6;
  float v;
  if (k < 256) v = emb[(size_t)tok[b*64 + t]*256 + k];
  else         v = img[b*256 + (k-256)];
  A[idx] = f2bf(v);
}

// WxT[i=(g*512+h)][k] = W_g[(512+k)*512 + h]  (bf16) -- x-part rows
__global__ void build_WxT(const float* __restrict__ Wu, const float* __restrict__ Wr,
                          const float* __restrict__ Wc, unsigned short* __restrict__ WxT){
  __shared__ float tile[64][65];
  int kb = blockIdx.x, hb = blockIdx.y, g = blockIdx.z;
  const float* Wg = g==0 ? Wu : (g==1 ? Wr : Wc);
  int tid = threadIdx.x, c = tid & 63, r4 = tid >> 6;
  #pragma unroll
  for (int i=0;i<16;i++){
    int kr = r4 + i*4;
    tile[kr][c] = Wg[(size_t)(512 + kb*64 + kr)*512 + hb*64 + c];
  }
  __syncthreads();
  #pragma unroll
  for (int i=0;i<16;i++){
    int hr = r4 + i*4;
    WxT[(size_t)(g*512 + hb*64 + hr)*512 + kb*64 + c] = f2bf(tile[c][hr]);
  }
}

// WrT[g][h][k] = W_g[k*512 + h] f32 -- state-part rows (k<512), transposed
__global__ void build_WrT(const float* __restrict__ Wu, const float* __restrict__ Wr,
                          const float* __restrict__ Wc, float* __restrict__ WrT){
  __shared__ float tile[64][65];
  int kb = blockIdx.x, hb = blockIdx.y, g = blockIdx.z;
  const float* Wg = g==0 ? Wu : (g==1 ? Wr : Wc);
  int tid = threadIdx.x, c = tid & 63, r4 = tid >> 6;
  #pragma unroll
  for (int i=0;i<16;i++){
    int kr = r4 + i*4;
    tile[kr][c] = Wg[(size_t)(kb*64 + kr)*512 + hb*64 + c];
  }
  __syncthreads();
  #pragma unroll
  for (int i=0;i<16;i++){
    int hr = r4 + i*4;
    WrT[((size_t)g*512 + hb*64 + hr)*512 + kb*64 + c] = tile[c][hr];
  }
}

// WoutT[v][h] bf16 (v padded to 10112, pad rows zero)
__global__ void build_WoutT(const float* __restrict__ Wo, unsigned short* __restrict__ WT){
  __shared__ float tile[64][65];
  int vb = blockIdx.x, hb = blockIdx.y;
  int tid = threadIdx.x, c = tid & 63, r4 = tid >> 6;
  #pragma unroll
  for (int i=0;i<16;i++){
    int hr = r4 + i*4;
    int v = vb*64 + c;
    tile[hr][c] = (v < Vv) ? Wo[(size_t)(hb*64 + hr)*Vv + v] : 0.f;
  }
  __syncthreads();
  #pragma unroll
  for (int i=0;i<16;i++){
    int vr = r4 + i*4;
    WT[(size_t)(vb*64 + vr)*512 + hb*64 + c] = f2bf(tile[c][vr]);
  }
}

// sb[0][bg][h] = init[bg*512+h]  (straight copy; sb layout [buf][bg64][k512])
__global__ void copy_s0(const float* __restrict__ init, float* __restrict__ sb){
  int idx = blockIdx.x*256 + threadIdx.x;  // 32768
  sb[idx] = init[idx];
}

// C = P @ Q^T, P[M][512], Q[N][512] bf16 row-major.
// MODE 0: pre-GEMM  P=WxT(1536), Q=Apre(4096); C -> preT[t][g][h][b], +b_u/+b_r by g
// MODE 1: logits    P=Alog(4096), Q=WoutT(10112); C -> out[b][t][v], +b_out, v<10000
template<int MODE>
__global__ __launch_bounds__(256) void gemm_bf16(
    const unsigned short* __restrict__ P, const unsigned short* __restrict__ Q,
    float* __restrict__ C, const float* __restrict__ bias0, const float* __restrict__ bias1)
{
  __shared__ __align__(16) unsigned short As[128*72];
  __shared__ __align__(16) unsigned short Bs[128*72];
  int tid = threadIdx.x;
  int lane = tid & 63, wave = tid >> 6;
  int wm = wave >> 1, wn = wave & 1;
  int m0 = blockIdx.y * 128, n0 = blockIdx.x * 128;
  f32x4 acc[4][4] = {};
  int r = tid >> 1, seg = tid & 1;
  const uint4* gp = (const uint4*)(P + (size_t)(m0 + r)*512 + seg*32);
  const uint4* gq = (const uint4*)(Q + (size_t)(n0 + r)*512 + seg*32);
  uint4* lp = (uint4*)(As + r*72 + seg*32);
  uint4* lq = (uint4*)(Bs + r*72 + seg*32);
  for (int kt = 0; kt < 8; ++kt) {
    uint4 a0 = gp[kt*8+0], a1 = gp[kt*8+1], a2 = gp[kt*8+2], a3 = gp[kt*8+3];
    uint4 b0 = gq[kt*8+0], b1 = gq[kt*8+1], b2 = gq[kt*8+2], b3 = gq[kt*8+3];
    if (kt) __syncthreads();
    lp[0]=a0; lp[1]=a1; lp[2]=a2; lp[3]=a3;
    lq[0]=b0; lq[1]=b1; lq[2]=b2; lq[3]=b3;
    __syncthreads();
    #pragma unroll
    for (int ks = 0; ks < 2; ++ks) {
      short8 a[4], b[4];
      int ko = ks*32 + (lane>>4)*8;
      #pragma unroll
      for (int f=0; f<4; ++f){
        a[f] = *(const short8*)(As + (wm*64 + f*16 + (lane&15))*72 + ko);
        b[f] = *(const short8*)(Bs + (wn*64 + f*16 + (lane&15))*72 + ko);
      }
      #pragma unroll
      for (int i=0;i<4;++i)
        #pragma unroll
        for (int j=0;j<4;++j)
          acc[i][j] = __builtin_amdgcn_mfma_f32_16x16x32_bf16(a[i], b[j], acc[i][j], 0,0,0);
    }
  }
  int rowbase = (lane>>4)*4;
  int col = lane & 15;
  #pragma unroll
  for (int i=0;i<4;++i){
    #pragma unroll
    for (int j=0;j<4;++j){
      int nJ = n0 + wn*64 + j*16 + col;
      #pragma unroll
      for (int rr=0; rr<4; ++rr){
        int mI = m0 + wm*64 + i*16 + rowbase + rr;
        float v = acc[i][j][rr];
        if (MODE == 0) {
          int g = mI >> 9, hh = mI & 511;
          if (g == 0) v += bias0[hh];
          else if (g == 1) v += bias1[hh];
          C[(size_t)(nJ>>6)*98304 + (size_t)mI*64 + (nJ&63)] = v;
        } else {
          if (nJ < Vv) {
            v += bias0[nJ];
            int t = mI >> 6, b = mI & 63;
            C[(size_t)b*640000 + (size_t)t*Vv + nJ] = v;
          }
        }
      }
    }
  }
}

// Recurrence v3: 256 wgs x 512 thr, cooperative. Group = blockIdx&7 (8 groups,
// 32 wgs each, 8 batches). wg owns 16 h-cols; wave owns 2 h; lane = (bs,ks):
// ks=k-split(32), bs=b-split(2x4). Weights pinned in 96 VGPRs (asm). State
// sL[b][k] -> conflict-free b32 reads. In-wave shfl_xor fold (no red buffer).
// Cross-wg: relaxed agent atomics only (no fences/invalidates).
__global__ __launch_bounds__(512, 2) void recur3(
    const float* __restrict__ WrT, const float* __restrict__ preT,
    const float* __restrict__ bc, float* __restrict__ sb,
    unsigned short* __restrict__ Alog, float* __restrict__ fstate,
    unsigned int* __restrict__ ctr)
{
  __shared__ float sL[4096];     // state [b8][k512]
  int tid = threadIdx.x;
  int lane = tid & 63;
  int wv = tid >> 6;
  int bs = lane >> 5;
  int ks = lane & 31;
  int wg = blockIdx.x;
  int g = wg & 7;
  int wgi = wg >> 3;
  int h0 = wgi * 16;

  // weights: w[hh][g3][i] = W_g3[k=i*32+ks][h0+wv*2+hh]; pinned via asm
  float w[2][3][16];
  #pragma unroll
  for (int hh=0; hh<2; ++hh)
    #pragma unroll
    for (int g3=0; g3<3; ++g3) {
      const float* wp = WrT + ((size_t)g3*512 + h0 + wv*2 + hh)*512 + ks;
      #pragma unroll
      for (int i=0; i<16; ++i) w[hh][g3][i] = wp[i*32];
    }
  #pragma unroll
  for (int hh=0; hh<2; ++hh)
    #pragma unroll
    for (int g3=0; g3<3; ++g3)
      #pragma unroll
      for (int i=0; i<16; ++i)
        asm volatile("" : "+v"(w[hh][g3][i]));

  // writer decode: lanes ks<8 of each half-wave own one (h,b) output
  int hh_w = (ks>>2)&1, bb_w = ks&3;
  int b_w = bs*4 + bb_w;
  int h_w = h0 + wv*2 + hh_w;
  int bg_w = g*8 + b_w;
  bool wr = (ks < 8);
  float bch = wr ? bc[h_w] : 0.f;
  int lb0 = ks&1, lb1 = (ks>>1)&1, lb2 = (ks>>2)&1;

  unsigned int tgt = 32;
  for (int t = 0; t < 64; ++t) {
    // stage state -> LDS (coherent b32 loads, coalesced; conflict-free ds writes)
    const float* srcp = sb + (size_t)(t&1)*32768 + g*4096;
    #pragma unroll
    for (int j=0; j<8; ++j)
      sL[tid + 512*j] = __hip_atomic_load(srcp + tid + 512*j,
                          __ATOMIC_RELAXED, __HIP_MEMORY_SCOPE_AGENT);
    // prefetch pre-activations (latency hidden under dot)
    float ptU=0.f, ptR=0.f, ptC=0.f;
    if (wr) {
      const float* pt = preT + (size_t)t*98304;
      ptU = pt[0*32768 + h_w*64 + bg_w];
      ptR = pt[1*32768 + h_w*64 + bg_w];
      ptC = pt[2*32768 + h_w*64 + bg_w];
    }
    __syncthreads();

    // partial dots: thread covers h'={wv*2,+1}, b={bs*4..+3}, k={ks+32i}
    float acc[2][3][4];
    #pragma unroll
    for (int hh=0; hh<2; ++hh)
      #pragma unroll
      for (int g3=0; g3<3; ++g3)
        #pragma unroll
        for (int bb=0; bb<4; ++bb) acc[hh][g3][bb] = 0.f;
    #pragma unroll
    for (int i=0; i<16; ++i){
      int k = ks + 32*i;
      float s0 = sL[(bs*4+0)*512 + k];
      float s1 = sL[(bs*4+1)*512 + k];
      float s2 = sL[(bs*4+2)*512 + k];
      float s3 = sL[(bs*4+3)*512 + k];
      #pragma unroll
      for (int hh=0; hh<2; ++hh)
        #pragma unroll
        for (int g3=0; g3<3; ++g3){
          float wv_ = w[hh][g3][i];
          acc[hh][g3][0] += s0 * wv_;
          acc[hh][g3][1] += s1 * wv_;
          acc[hh][g3][2] += s2 * wv_;
          acc[hh][g3][3] += s3 * wv_;
        }
    }

    // in-wave fold over ks bits 0..4; slot-split so lane ks ends with
    // (U,R,C) for (hh=(ks>>2)&1, bb=ks&3), replicated over ks>>3.
    float n12[2][3][2];
    #pragma unroll
    for (int hh=0; hh<2; ++hh)
      #pragma unroll
      for (int g3=0; g3<3; ++g3)
        #pragma unroll
        for (int bh=0; bh<2; ++bh){
          float snd = lb0 ? acc[hh][g3][bh*2+0] : acc[hh][g3][bh*2+1];
          float kp  = lb0 ? acc[hh][g3][bh*2+1] : acc[hh][g3][bh*2+0];
          n12[hh][g3][bh] = kp + __shfl_xor(snd, 1, 64);
        }
    float n6[2][3];
    #pragma unroll
    for (int hh=0; hh<2; ++hh)
      #pragma unroll
      for (int g3=0; g3<3; ++g3){
        float snd = lb1 ? n12[hh][g3][0] : n12[hh][g3][1];
        float kp  = lb1 ? n12[hh][g3][1] : n12[hh][g3][0];
        n6[hh][g3] = kp + __shfl_xor(snd, 2, 64);
      }
    float n3[3];
    #pragma unroll
    for (int g3=0; g3<3; ++g3){
      float snd = lb2 ? n6[0][g3] : n6[1][g3];
      float kp  = lb2 ? n6[1][g3] : n6[0][g3];
      n3[g3] = kp + __shfl_xor(snd, 4, 64);
    }
    #pragma unroll
    for (int g3=0; g3<3; ++g3) n3[g3] += __shfl_xor(n3[g3], 8, 64);
    #pragma unroll
    for (int g3=0; g3<3; ++g3) n3[g3] += __shfl_xor(n3[g3], 16, 64);

    if (wr) {
      float sold = sL[b_w*512 + h_w];
      float gu = 1.f/(1.f + __expf(-(n3[0] + ptU)));
      float gr = 1.f/(1.f + __expf(-(n3[1] + ptR)));
      float rv = tanhf(gr * (n3[2] + ptC) + bch);
      float ns = rv*(1.f - gu) + gu*sold;
      __hip_atomic_store(sb + (size_t)((t+1)&1)*32768 + g*4096 + b_w*512 + h_w,
                         ns, __ATOMIC_RELAXED, __HIP_MEMORY_SCOPE_AGENT);
      Alog[((size_t)(t*64) + bg_w)*512 + h_w] = f2bf(ns);
      if (t == 63) fstate[(size_t)bg_w*512 + h_w] = ns;
    }
    if (t < 63) {
      __syncthreads();   // drains vmcnt: all state stores completed before bump
      if (tid == 0) {
        __hip_atomic_fetch_add(&ctr[g], 1u, __ATOMIC_RELAXED, __HIP_MEMORY_SCOPE_AGENT);
        while (__hip_atomic_load(&ctr[g], __ATOMIC_RELAXED, __HIP_MEMORY_SCOPE_AGENT) < tgt)
          __builtin_amdgcn_s_sleep(1);
      }
      tgt += 32;
      __syncthreads();
    }
  }
}

extern "C" void kernel_launch(void* const* d_in, const int* in_sizes, int n_in,
                              void* d_out, int out_size, void* d_ws, size_t ws_size,
                              hipStream_t stream){
  const int*   tok  = (const int*)  d_in[0];
  const float* img  = (const float*)d_in[1];
  const float* init = (const float*)d_in[2];
  const float* emb  = (const float*)d_in[3];
  const float* Wu   = (const float*)d_in[4];
  const float* bu   = (const float*)d_in[5];
  const float* Wr   = (const float*)d_in[6];
  const float* br   = (const float*)d_in[7];
  const float* Wc   = (const float*)d_in[8];
  const float* bcp  = (const float*)d_in[9];
  const float* Wo   = (const float*)d_in[10];
  const float* bo   = (const float*)d_in[11];
  float* out = (float*)d_out;

  char* ws = (char*)d_ws;
  size_t off = 0;
  unsigned short* Apre = (unsigned short*)(ws + off); off += (size_t)4096*512*2;      // 4 MB
  unsigned short* WxT  = (unsigned short*)(ws + off); off += (size_t)1536*512*2;      // 1.5 MB
  float* preT          = (float*)(ws + off);          off += (size_t)64*3*512*64*4;   // 25.2 MB
  unsigned short* Alog = (unsigned short*)(ws + off); off += (size_t)4096*512*2;      // 4 MB
  unsigned short* WoT  = (unsigned short*)(ws + off); off += (size_t)VPAD*512*2;      // 10.4 MB
  float* WrTbuf        = (float*)(ws + off);          off += (size_t)3*512*512*4;     // 3 MB
  float* sb            = (float*)(ws + off);          off += (size_t)2*64*512*4;      // 256 KB
  unsigned int* ctr    = (unsigned int*)(ws + off);   off += 256;

  build_Apre <<<8192, 256, 0, stream>>>(tok, emb, img, Apre);
  build_WxT  <<<dim3(8,8,3), 256, 0, stream>>>(Wu, Wr, Wc, WxT);
  build_WrT  <<<dim3(8,8,3), 256, 0, stream>>>(Wu, Wr, Wc, WrTbuf);
  build_WoutT<<<dim3(158,8), 256, 0, stream>>>(Wo, WoT);
  copy_s0    <<<128, 256, 0, stream>>>(init, sb);

  gemm_bf16<0><<<dim3(32,12), 256, 0, stream>>>(WxT, Apre, preT, bu, br);

  hipMemsetAsync(ctr, 0, 256, stream);
  float* fstate = out + (size_t)40960000;
  void* args[7] = { (void*)&WrTbuf, (void*)&preT, (void*)&bcp, (void*)&sb,
                    (void*)&Alog, (void*)&fstate, (void*)&ctr };
  hipLaunchCooperativeKernel((void*)recur3, dim3(256), dim3(512), args, 0, stream);

  gemm_bf16<1><<<dim3(79,32), 256, 0, stream>>>(Alog, WoT, out, bo, nullptr);
}